// Round 1
// baseline (2103.788 us; speedup 1.0000x reference)
//
#include <hip/hip_runtime.h>

#define N_NODES 50000
#define N_EDGES 800000
#define D_FEAT 512
#define N_LAYERS 3
#define LN_EPS 1e-5f

// ---------------- graph preprocessing ----------------

__global__ __launch_bounds__(256) void count_deg_kernel(const int* __restrict__ ei,
                                                        int* __restrict__ cnt) {
  int e = blockIdx.x * 256 + threadIdx.x;
  if (e < N_EDGES) atomicAdd(&cnt[ei[N_EDGES + e]], 1);
}

// single-workgroup exclusive scan over node in-degree counts; also emits inv_sqrt(deg+1)
__global__ __launch_bounds__(1024) void scan_kernel(const int* __restrict__ cnt,
                                                    int* __restrict__ rowoff,
                                                    float* __restrict__ inv_sqrt) {
  __shared__ int sd[1024];
  int tid = threadIdx.x;
  int carry = 0;
  for (int base = 0; base < N_NODES; base += 1024) {
    int i = base + tid;
    int v = (i < N_NODES) ? cnt[i] : 0;
    sd[tid] = v;
    __syncthreads();
    for (int off = 1; off < 1024; off <<= 1) {
      int t = (tid >= off) ? sd[tid - off] : 0;
      __syncthreads();
      sd[tid] += t;
      __syncthreads();
    }
    int incl = sd[tid];
    if (i < N_NODES) {
      rowoff[i] = carry + incl - v;          // exclusive prefix
      inv_sqrt[i] = rsqrtf(1.0f + (float)v); // deg includes self-loop
    }
    carry += sd[1023];
    __syncthreads();
  }
  if (tid == 0) rowoff[N_NODES] = carry;
}

__global__ __launch_bounds__(256) void fill_csr_kernel(const int* __restrict__ ei,
                                                       const int* __restrict__ rowoff,
                                                       int* __restrict__ cursor,
                                                       int* __restrict__ csr_src) {
  int e = blockIdx.x * 256 + threadIdx.x;
  if (e < N_EDGES) {
    int d = ei[N_EDGES + e];
    int p = atomicAdd(&cursor[d], 1);
    csr_src[rowoff[d] + p] = ei[e];
  }
}

// ---------------- fp32 tiled GEMM:  C[M,512] = A[M,512] @ W[512,512] + bias ----------------
// 64x64 tile, BK=16, 256 threads, 4x4 microtile per thread.

#define BM 64
#define BN 64
#define BK 16

__global__ __launch_bounds__(256) void gemm_bias_kernel(const float* __restrict__ A,
                                                        const float* __restrict__ W,
                                                        const float* __restrict__ bias,
                                                        float* __restrict__ C, int M) {
  __shared__ float As[BK][BM + 1];
  __shared__ float Bs[BK][BN];

  int tid = threadIdx.x;
  int tx = tid & 15;
  int ty = tid >> 4;
  int m0 = blockIdx.y * BM;
  int n0 = blockIdx.x * BN;

  float acc[4][4] = {};

  for (int k0 = 0; k0 < D_FEAT; k0 += BK) {
    // load A tile 64x16 (transposed into As[k][m]); 4 consecutive k per thread
    {
      int idx = tid * 4;
      int m = idx >> 4;
      int kk = idx & 15;
      int gm = m0 + m;
      float4 v = make_float4(0.f, 0.f, 0.f, 0.f);
      if (gm < M) v = *(const float4*)(A + (size_t)gm * D_FEAT + k0 + kk);
      As[kk + 0][m] = v.x;
      As[kk + 1][m] = v.y;
      As[kk + 2][m] = v.z;
      As[kk + 3][m] = v.w;
    }
    // load B tile 16x64; 4 consecutive n per thread
    {
      int idx = tid * 4;
      int kk = idx >> 6;
      int n = idx & 63;
      float4 v = *(const float4*)(W + (size_t)(k0 + kk) * D_FEAT + n0 + n);
      *(float4*)&Bs[kk][n] = v;
    }
    __syncthreads();

#pragma unroll
    for (int kk = 0; kk < BK; ++kk) {
      float4 b = *(const float4*)&Bs[kk][tx * 4];
      float a0 = As[kk][ty * 4 + 0];
      float a1 = As[kk][ty * 4 + 1];
      float a2 = As[kk][ty * 4 + 2];
      float a3 = As[kk][ty * 4 + 3];
      acc[0][0] += a0 * b.x; acc[0][1] += a0 * b.y; acc[0][2] += a0 * b.z; acc[0][3] += a0 * b.w;
      acc[1][0] += a1 * b.x; acc[1][1] += a1 * b.y; acc[1][2] += a1 * b.z; acc[1][3] += a1 * b.w;
      acc[2][0] += a2 * b.x; acc[2][1] += a2 * b.y; acc[2][2] += a2 * b.z; acc[2][3] += a2 * b.w;
      acc[3][0] += a3 * b.x; acc[3][1] += a3 * b.y; acc[3][2] += a3 * b.z; acc[3][3] += a3 * b.w;
    }
    __syncthreads();
  }

  float4 bb = *(const float4*)(bias + n0 + tx * 4);
#pragma unroll
  for (int i = 0; i < 4; ++i) {
    int gm = m0 + ty * 4 + i;
    if (gm < M) {
      float4 o;
      o.x = acc[i][0] + bb.x;
      o.y = acc[i][1] + bb.y;
      o.z = acc[i][2] + bb.z;
      o.w = acc[i][3] + bb.w;
      *(float4*)(C + (size_t)gm * D_FEAT + n0 + tx * 4) = o;
    }
  }
}

// ---------------- fused aggregate + self-loop + LayerNorm + ReLU ----------------
// one block (128 threads) per node; each thread owns 4 consecutive features.

__global__ __launch_bounds__(128) void agg_ln_relu_kernel(const float* __restrict__ ht,
                                                          const int* __restrict__ rowoff,
                                                          const int* __restrict__ csr_src,
                                                          const float* __restrict__ inv_sqrt,
                                                          const float* __restrict__ gamma,
                                                          const float* __restrict__ beta,
                                                          float* __restrict__ hout) {
  int n = blockIdx.x;
  int tid = threadIdx.x;
  int c4 = tid * 4;

  float4 acc = make_float4(0.f, 0.f, 0.f, 0.f);
  int beg = rowoff[n];
  int end = rowoff[n + 1];
  float isn = inv_sqrt[n];

  for (int e = beg; e < end; ++e) {
    int s = csr_src[e];
    float w = isn * inv_sqrt[s];
    float4 v = *(const float4*)(ht + (size_t)s * D_FEAT + c4);
    acc.x += w * v.x; acc.y += w * v.y; acc.z += w * v.z; acc.w += w * v.w;
  }
  // self-loop: ht[n] / deg, 1/deg == inv_sqrt[n]^2
  {
    float w = isn * isn;
    float4 v = *(const float4*)(ht + (size_t)n * D_FEAT + c4);
    acc.x += w * v.x; acc.y += w * v.y; acc.z += w * v.z; acc.w += w * v.w;
  }

  // block reduction for mean / var over 512 features
  float s = acc.x + acc.y + acc.z + acc.w;
  float s2 = acc.x * acc.x + acc.y * acc.y + acc.z * acc.z + acc.w * acc.w;
  for (int off = 32; off > 0; off >>= 1) {
    s += __shfl_down(s, off);
    s2 += __shfl_down(s2, off);
  }
  __shared__ float red[4];
  int lane = tid & 63;
  int wid = tid >> 6;
  if (lane == 0) { red[wid * 2] = s; red[wid * 2 + 1] = s2; }
  __syncthreads();
  float stot = red[0] + red[2];
  float s2tot = red[1] + red[3];

  const float inv_d = 1.0f / (float)D_FEAT;
  float mu = stot * inv_d;
  float var = s2tot * inv_d - mu * mu;
  float rstd = rsqrtf(var + LN_EPS);

  float4 g = *(const float4*)(gamma + c4);
  float4 b = *(const float4*)(beta + c4);
  float4 o;
  o.x = fmaxf(g.x * (acc.x - mu) * rstd + b.x, 0.f);
  o.y = fmaxf(g.y * (acc.y - mu) * rstd + b.y, 0.f);
  o.z = fmaxf(g.z * (acc.z - mu) * rstd + b.z, 0.f);
  o.w = fmaxf(g.w * (acc.w - mu) * rstd + b.w, 0.f);
  *(float4*)(hout + (size_t)n * D_FEAT + c4) = o;
}

// ---------------- launch ----------------

extern "C" void kernel_launch(void* const* d_in, const int* in_sizes, int n_in,
                              void* d_out, int out_size, void* d_ws, size_t ws_size,
                              hipStream_t stream) {
  const float* x      = (const float*)d_in[0];
  const int*   ei     = (const int*)d_in[1];
  const float* Ws     = (const float*)d_in[2];
  const float* bs     = (const float*)d_in[3];
  const float* gammas = (const float*)d_in[4];
  const float* betas  = (const float*)d_in[5];
  float* out = (float*)d_out;

  // workspace layout
  float* hbuf  = (float*)d_ws;                          // 25.6M floats
  float* htbuf = hbuf + (size_t)N_NODES * D_FEAT;       // 25.6M floats
  int* deg_cnt = (int*)(htbuf + (size_t)N_NODES * D_FEAT); // 50000
  int* rowoff  = deg_cnt + N_NODES;                     // 50001
  int* cursor  = rowoff + (N_NODES + 1);                // 50000
  int* csr_src = cursor + N_NODES;                      // 800000
  float* inv_sqrt = (float*)(csr_src + N_EDGES);        // 50000

  hipMemsetAsync(deg_cnt, 0, N_NODES * sizeof(int), stream);
  hipMemsetAsync(cursor, 0, N_NODES * sizeof(int), stream);

  count_deg_kernel<<<(N_EDGES + 255) / 256, 256, 0, stream>>>(ei, deg_cnt);
  scan_kernel<<<1, 1024, 0, stream>>>(deg_cnt, rowoff, inv_sqrt);
  fill_csr_kernel<<<(N_EDGES + 255) / 256, 256, 0, stream>>>(ei, rowoff, cursor, csr_src);

  const float* hin = x;
  dim3 ggrid(D_FEAT / BN, (N_NODES + BM - 1) / BM);
  for (int l = 0; l < N_LAYERS; ++l) {
    gemm_bias_kernel<<<ggrid, 256, 0, stream>>>(hin, Ws + (size_t)l * D_FEAT * D_FEAT,
                                                bs + (size_t)l * D_FEAT, htbuf, N_NODES);
    float* hout = (l == N_LAYERS - 1) ? out : hbuf;
    agg_ln_relu_kernel<<<N_NODES, 128, 0, stream>>>(htbuf, rowoff, csr_src, inv_sqrt,
                                                    gammas + (size_t)l * D_FEAT,
                                                    betas + (size_t)l * D_FEAT, hout);
    hin = hbuf;
  }
}

// Round 2
// 1415.515 us; speedup vs baseline: 1.4862x; 1.4862x over previous
//
#include <hip/hip_runtime.h>

#define N_NODES 50000
#define N_EDGES 800000
#define D_FEAT 512
#define N_LAYERS 3
#define LN_EPS 1e-5f
#define M_PAD 50048  // 391 * 128, GEMM M padding

typedef __attribute__((ext_vector_type(8))) short short8;
typedef __attribute__((ext_vector_type(4))) float f32x4;

__device__ __forceinline__ unsigned short f2bf(float f) {
  union { float f; unsigned u; } v; v.f = f;
  unsigned r = v.u + 0x7fffu + ((v.u >> 16) & 1u);  // RNE
  return (unsigned short)(r >> 16);
}
__device__ __forceinline__ float bf2f(unsigned short b) {
  union { unsigned u; float f; } v; v.u = ((unsigned)b) << 16;
  return v.f;
}

__device__ __forceinline__ void gl_lds16(const unsigned short* g, unsigned short* l) {
  __builtin_amdgcn_global_load_lds((const __attribute__((address_space(1))) unsigned int*)g,
                                   (__attribute__((address_space(3))) unsigned int*)l, 16, 0, 0);
}

// ---------------- graph preprocessing ----------------

__global__ __launch_bounds__(256) void count_deg_kernel(const int* __restrict__ ei,
                                                        int* __restrict__ cnt) {
  int e = blockIdx.x * 256 + threadIdx.x;
  if (e < N_EDGES) atomicAdd(&cnt[ei[N_EDGES + e]], 1);
}

__global__ __launch_bounds__(1024) void scan_kernel(const int* __restrict__ cnt,
                                                    int* __restrict__ rowoff,
                                                    float* __restrict__ inv_sqrt) {
  __shared__ int sd[1024];
  int tid = threadIdx.x;
  int carry = 0;
  for (int base = 0; base < N_NODES; base += 1024) {
    int i = base + tid;
    int v = (i < N_NODES) ? cnt[i] : 0;
    sd[tid] = v;
    __syncthreads();
    for (int off = 1; off < 1024; off <<= 1) {
      int t = (tid >= off) ? sd[tid - off] : 0;
      __syncthreads();
      sd[tid] += t;
      __syncthreads();
    }
    int incl = sd[tid];
    if (i < N_NODES) {
      rowoff[i] = carry + incl - v;
      inv_sqrt[i] = rsqrtf(1.0f + (float)v);
    }
    carry += sd[1023];
    __syncthreads();
  }
  if (tid == 0) rowoff[N_NODES] = carry;
}

__global__ __launch_bounds__(256) void fill_csr_kernel(const int* __restrict__ ei,
                                                       const int* __restrict__ rowoff,
                                                       int* __restrict__ cursor,
                                                       int* __restrict__ csr_src) {
  int e = blockIdx.x * 256 + threadIdx.x;
  if (e < N_EDGES) {
    int d = ei[N_EDGES + e];
    int p = atomicAdd(&cursor[d], 1);
    csr_src[rowoff[d] + p] = ei[e];
  }
}

// ---------------- fp32 -> split bf16 conversions ----------------

// x [N_NODES,512] -> Ah/Al [M_PAD,512]; pad rows zeroed
__global__ __launch_bounds__(256) void convert_x_kernel(const float* __restrict__ x,
                                                        unsigned short* __restrict__ Ah,
                                                        unsigned short* __restrict__ Al) {
  size_t i4 = ((size_t)blockIdx.x * 256 + threadIdx.x) * 4;
  int row = (int)(i4 >> 9);
  ushort4 h, l;
  if (row < N_NODES) {
    float4 v = *(const float4*)(x + i4);
    h.x = f2bf(v.x); l.x = f2bf(v.x - bf2f(h.x));
    h.y = f2bf(v.y); l.y = f2bf(v.y - bf2f(h.y));
    h.z = f2bf(v.z); l.z = f2bf(v.z - bf2f(h.z));
    h.w = f2bf(v.w); l.w = f2bf(v.w - bf2f(h.w));
  } else {
    h.x = h.y = h.z = h.w = 0;
    l.x = l.y = l.z = l.w = 0;
  }
  *(ushort4*)(Ah + i4) = h;
  *(ushort4*)(Al + i4) = l;
}

// W [k][n] fp32 -> Wt hi/lo [n][k] bf16 (transposed, split)
__global__ __launch_bounds__(256) void wconv_kernel(const float* __restrict__ W,
                                                    unsigned short* __restrict__ Bh,
                                                    unsigned short* __restrict__ Bl) {
  __shared__ float t[64][65];
  int n0 = blockIdx.x * 64, k0 = blockIdx.y * 64;
  int tid = threadIdx.x;
  int c = tid & 63, r4 = tid >> 6;
#pragma unroll
  for (int r = 0; r < 64; r += 4)
    t[r4 + r][c] = W[(size_t)(k0 + r4 + r) * D_FEAT + n0 + c];
  __syncthreads();
#pragma unroll
  for (int r = 0; r < 64; r += 4) {
    float v = t[c][r4 + r];  // k-local = c, n-local = r4+r
    unsigned short h = f2bf(v);
    size_t o = (size_t)(n0 + r4 + r) * D_FEAT + k0 + c;
    Bh[o] = h;
    Bl[o] = f2bf(v - bf2f(h));
  }
}

// ---------------- split-bf16 MFMA GEMM: C[M,512] = A @ W + bias ----------------
// 128x128 tile, BK=32, 256 threads (4 waves, 2x2 of 64x64), 3 MFMA products.

__global__ __launch_bounds__(256, 3) void mfma_gemm_kernel(
    const unsigned short* __restrict__ Ah, const unsigned short* __restrict__ Al,
    const unsigned short* __restrict__ Bh, const unsigned short* __restrict__ Bl,
    const float* __restrict__ bias, float* __restrict__ C) {
  __shared__ unsigned short sAh[128 * 32], sAl[128 * 32], sBh[128 * 32], sBl[128 * 32];

  int tid = threadIdx.x;
  int wave = tid >> 6, lane = tid & 63;
  int m0 = blockIdx.x * 128, n0 = blockIdx.y * 128;

  // staging: wave handles chunks (wave*2+c), c=0,1; each chunk = 16 LDS rows of 64B
  int r0 = (wave * 2 + 0) * 16 + (lane >> 2);
  int r1 = (wave * 2 + 1) * 16 + (lane >> 2);
  int s0 = (lane & 3) ^ ((r0 >> 1) & 3);  // XOR-swizzled k-quad slot
  int s1 = (lane & 3) ^ ((r1 >> 1) & 3);
  size_t gA0 = (size_t)(m0 + r0) * D_FEAT + s0 * 8;
  size_t gA1 = (size_t)(m0 + r1) * D_FEAT + s1 * 8;
  size_t gB0 = (size_t)(n0 + r0) * D_FEAT + s0 * 8;
  size_t gB1 = (size_t)(n0 + r1) * D_FEAT + s1 * 8;
  int l0 = (wave * 2 + 0) * 512;  // LDS chunk base (ushort units); lane data lands at +lane*8
  int l1 = (wave * 2 + 1) * 512;

  int q = lane >> 4, fr = lane & 15;
  int wm = (wave >> 1) * 64, wn = (wave & 1) * 64;
  int aoff[4], boff[4];
#pragma unroll
  for (int i = 0; i < 4; ++i) {
    int row = wm + i * 16 + fr;
    aoff[i] = row * 32 + (q ^ ((row >> 1) & 3)) * 8;
  }
#pragma unroll
  for (int j = 0; j < 4; ++j) {
    int row = wn + j * 16 + fr;
    boff[j] = row * 32 + (q ^ ((row >> 1) & 3)) * 8;
  }

  f32x4 acc[4][4];
#pragma unroll
  for (int i = 0; i < 4; ++i)
#pragma unroll
    for (int j = 0; j < 4; ++j) acc[i][j] = (f32x4)0.0f;

  for (int k0 = 0; k0 < D_FEAT; k0 += 32) {
    gl_lds16(Ah + gA0 + k0, sAh + l0);
    gl_lds16(Ah + gA1 + k0, sAh + l1);
    gl_lds16(Al + gA0 + k0, sAl + l0);
    gl_lds16(Al + gA1 + k0, sAl + l1);
    gl_lds16(Bh + gB0 + k0, sBh + l0);
    gl_lds16(Bh + gB1 + k0, sBh + l1);
    gl_lds16(Bl + gB0 + k0, sBl + l0);
    gl_lds16(Bl + gB1 + k0, sBl + l1);
    __syncthreads();

    short8 ah[4], bb[4], t[4];
#pragma unroll
    for (int i = 0; i < 4; ++i) ah[i] = *(const short8*)(sAh + aoff[i]);
#pragma unroll
    for (int j = 0; j < 4; ++j) bb[j] = *(const short8*)(sBh + boff[j]);
#pragma unroll
    for (int i = 0; i < 4; ++i)
#pragma unroll
      for (int j = 0; j < 4; ++j)
        acc[i][j] = __builtin_amdgcn_mfma_f32_16x16x32_bf16(ah[i], bb[j], acc[i][j], 0, 0, 0);
    // lo(A) * hi(B)
#pragma unroll
    for (int i = 0; i < 4; ++i) t[i] = *(const short8*)(sAl + aoff[i]);
#pragma unroll
    for (int i = 0; i < 4; ++i)
#pragma unroll
      for (int j = 0; j < 4; ++j)
        acc[i][j] = __builtin_amdgcn_mfma_f32_16x16x32_bf16(t[i], bb[j], acc[i][j], 0, 0, 0);
    // hi(A) * lo(B)
#pragma unroll
    for (int j = 0; j < 4; ++j) bb[j] = *(const short8*)(sBl + boff[j]);
#pragma unroll
    for (int i = 0; i < 4; ++i)
#pragma unroll
      for (int j = 0; j < 4; ++j)
        acc[i][j] = __builtin_amdgcn_mfma_f32_16x16x32_bf16(ah[i], bb[j], acc[i][j], 0, 0, 0);
    __syncthreads();
  }

  // epilogue: D[row = q*4+r][col = fr] per 16x16 subtile
  float bj[4];
#pragma unroll
  for (int j = 0; j < 4; ++j) bj[j] = bias[n0 + wn + j * 16 + fr];
#pragma unroll
  for (int i = 0; i < 4; ++i) {
    int gm0 = m0 + wm + i * 16 + q * 4;
#pragma unroll
    for (int j = 0; j < 4; ++j) {
      int gn = n0 + wn + j * 16 + fr;
#pragma unroll
      for (int r = 0; r < 4; ++r) {
        int gm = gm0 + r;
        if (gm < N_NODES) C[(size_t)gm * D_FEAT + gn] = acc[i][j][r] + bj[j];
      }
    }
  }
}

// ---------------- fused aggregate + self-loop + LayerNorm + ReLU ----------------
// LAST=true: write fp32 to hout; else write bf16 hi/lo planes for next GEMM.

template <bool LAST>
__global__ __launch_bounds__(128) void agg_ln_relu_kernel(const float* __restrict__ ht,
                                                          const int* __restrict__ rowoff,
                                                          const int* __restrict__ csr_src,
                                                          const float* __restrict__ inv_sqrt,
                                                          const float* __restrict__ gamma,
                                                          const float* __restrict__ beta,
                                                          float* __restrict__ hout,
                                                          unsigned short* __restrict__ ph,
                                                          unsigned short* __restrict__ pl) {
  int n = blockIdx.x;
  int tid = threadIdx.x;
  int c4 = tid * 4;

  float4 acc = make_float4(0.f, 0.f, 0.f, 0.f);
  int beg = rowoff[n];
  int end = rowoff[n + 1];
  float isn = inv_sqrt[n];

  for (int e = beg; e < end; ++e) {
    int s = csr_src[e];
    float w = isn * inv_sqrt[s];
    float4 v = *(const float4*)(ht + (size_t)s * D_FEAT + c4);
    acc.x += w * v.x; acc.y += w * v.y; acc.z += w * v.z; acc.w += w * v.w;
  }
  {
    float w = isn * isn;  // self-loop 1/deg
    float4 v = *(const float4*)(ht + (size_t)n * D_FEAT + c4);
    acc.x += w * v.x; acc.y += w * v.y; acc.z += w * v.z; acc.w += w * v.w;
  }

  float s = acc.x + acc.y + acc.z + acc.w;
  float s2 = acc.x * acc.x + acc.y * acc.y + acc.z * acc.z + acc.w * acc.w;
  for (int off = 32; off > 0; off >>= 1) {
    s += __shfl_down(s, off);
    s2 += __shfl_down(s2, off);
  }
  __shared__ float red[4];
  int lane = tid & 63;
  int wid = tid >> 6;
  if (lane == 0) { red[wid * 2] = s; red[wid * 2 + 1] = s2; }
  __syncthreads();
  float stot = red[0] + red[2];
  float s2tot = red[1] + red[3];

  const float inv_d = 1.0f / (float)D_FEAT;
  float mu = stot * inv_d;
  float var = s2tot * inv_d - mu * mu;
  float rstd = rsqrtf(var + LN_EPS);

  float4 g = *(const float4*)(gamma + c4);
  float4 b = *(const float4*)(beta + c4);
  float4 o;
  o.x = fmaxf(g.x * (acc.x - mu) * rstd + b.x, 0.f);
  o.y = fmaxf(g.y * (acc.y - mu) * rstd + b.y, 0.f);
  o.z = fmaxf(g.z * (acc.z - mu) * rstd + b.z, 0.f);
  o.w = fmaxf(g.w * (acc.w - mu) * rstd + b.w, 0.f);

  if (LAST) {
    *(float4*)(hout + (size_t)n * D_FEAT + c4) = o;
  } else {
    ushort4 h, l;
    h.x = f2bf(o.x); l.x = f2bf(o.x - bf2f(h.x));
    h.y = f2bf(o.y); l.y = f2bf(o.y - bf2f(h.y));
    h.z = f2bf(o.z); l.z = f2bf(o.z - bf2f(h.z));
    h.w = f2bf(o.w); l.w = f2bf(o.w - bf2f(h.w));
    size_t off = (size_t)n * D_FEAT + c4;
    *(ushort4*)(ph + off) = h;
    *(ushort4*)(pl + off) = l;
  }
}

// ---------------- launch ----------------

extern "C" void kernel_launch(void* const* d_in, const int* in_sizes, int n_in,
                              void* d_out, int out_size, void* d_ws, size_t ws_size,
                              hipStream_t stream) {
  const float* x      = (const float*)d_in[0];
  const int*   ei     = (const int*)d_in[1];
  const float* Ws     = (const float*)d_in[2];
  const float* bs     = (const float*)d_in[3];
  const float* gammas = (const float*)d_in[4];
  const float* betas  = (const float*)d_in[5];
  float* out = (float*)d_out;

  // workspace layout
  unsigned short* Ah  = (unsigned short*)d_ws;                  // M_PAD*512
  unsigned short* Al  = Ah + (size_t)M_PAD * D_FEAT;            // M_PAD*512
  unsigned short* Bth = Al + (size_t)M_PAD * D_FEAT;            // 512*512
  unsigned short* Btl = Bth + (size_t)D_FEAT * D_FEAT;          // 512*512
  float* ht           = (float*)(Btl + (size_t)D_FEAT * D_FEAT); // 50000*512 fp32
  int* deg_cnt  = (int*)(ht + (size_t)N_NODES * D_FEAT);
  int* rowoff   = deg_cnt + N_NODES;
  int* cursor   = rowoff + (N_NODES + 1);
  int* csr_src  = cursor + N_NODES;
  float* inv_sqrt = (float*)(csr_src + N_EDGES);

  hipMemsetAsync(deg_cnt, 0, N_NODES * sizeof(int), stream);
  hipMemsetAsync(cursor, 0, N_NODES * sizeof(int), stream);

  count_deg_kernel<<<(N_EDGES + 255) / 256, 256, 0, stream>>>(ei, deg_cnt);
  scan_kernel<<<1, 1024, 0, stream>>>(deg_cnt, rowoff, inv_sqrt);
  fill_csr_kernel<<<(N_EDGES + 255) / 256, 256, 0, stream>>>(ei, rowoff, cursor, csr_src);

  convert_x_kernel<<<(M_PAD * D_FEAT / 4) / 256, 256, 0, stream>>>(x, Ah, Al);

  dim3 ggrid(M_PAD / 128, D_FEAT / 128);
  for (int l = 0; l < N_LAYERS; ++l) {
    wconv_kernel<<<dim3(8, 8), 256, 0, stream>>>(Ws + (size_t)l * D_FEAT * D_FEAT, Bth, Btl);
    mfma_gemm_kernel<<<ggrid, 256, 0, stream>>>(Ah, Al, Bth, Btl, bs + (size_t)l * D_FEAT, ht);
    if (l < N_LAYERS - 1) {
      agg_ln_relu_kernel<false><<<N_NODES, 128, 0, stream>>>(
          ht, rowoff, csr_src, inv_sqrt, gammas + (size_t)l * D_FEAT,
          betas + (size_t)l * D_FEAT, nullptr, Ah, Al);
    } else {
      agg_ln_relu_kernel<true><<<N_NODES, 128, 0, stream>>>(
          ht, rowoff, csr_src, inv_sqrt, gammas + (size_t)l * D_FEAT,
          betas + (size_t)l * D_FEAT, out, nullptr, nullptr);
    }
  }
}

// Round 3
// 1030.435 us; speedup vs baseline: 2.0417x; 1.3737x over previous
//
#include <hip/hip_runtime.h>

#define N_NODES 50000
#define N_EDGES 800000
#define D_FEAT 512
#define N_LAYERS 3
#define LN_EPS 1e-5f
#define M_PAD 50048  // 391 * 128

typedef __attribute__((ext_vector_type(8))) short short8;
typedef __attribute__((ext_vector_type(8))) unsigned short u16x8;
typedef __attribute__((ext_vector_type(4))) float f32x4;

__device__ __forceinline__ unsigned short f2bf(float f) {
  union { float f; unsigned u; } v; v.f = f;
  unsigned r = v.u + 0x7fffu + ((v.u >> 16) & 1u);  // RNE
  return (unsigned short)(r >> 16);
}
__device__ __forceinline__ float bf2f(unsigned short b) {
  union { unsigned u; float f; } v; v.u = ((unsigned)b) << 16;
  return v.f;
}

__device__ __forceinline__ void gl_lds16(const unsigned short* g, unsigned short* l) {
  __builtin_amdgcn_global_load_lds((const __attribute__((address_space(1))) unsigned int*)g,
                                   (__attribute__((address_space(3))) unsigned int*)l, 16, 0, 0);
}

// ---------------- graph preprocessing ----------------

__global__ __launch_bounds__(256) void count_deg_kernel(const int* __restrict__ ei,
                                                        int* __restrict__ cnt) {
  int e = blockIdx.x * 256 + threadIdx.x;
  if (e < N_EDGES) atomicAdd(&cnt[ei[N_EDGES + e]], 1);
}

__global__ __launch_bounds__(1024) void scan_kernel(const int* __restrict__ cnt,
                                                    int* __restrict__ rowoff,
                                                    float* __restrict__ inv_sqrt) {
  __shared__ int sd[1024];
  int tid = threadIdx.x;
  int carry = 0;
  for (int base = 0; base < N_NODES; base += 1024) {
    int i = base + tid;
    int v = (i < N_NODES) ? cnt[i] : 0;
    sd[tid] = v;
    __syncthreads();
    for (int off = 1; off < 1024; off <<= 1) {
      int t = (tid >= off) ? sd[tid - off] : 0;
      __syncthreads();
      sd[tid] += t;
      __syncthreads();
    }
    int incl = sd[tid];
    if (i < N_NODES) {
      rowoff[i] = carry + incl - v;
      inv_sqrt[i] = rsqrtf(1.0f + (float)v);
    }
    carry += sd[1023];
    __syncthreads();
  }
  if (tid == 0) rowoff[N_NODES] = carry;
}

__global__ __launch_bounds__(256) void fill_csr_kernel(const int* __restrict__ ei,
                                                       const int* __restrict__ rowoff,
                                                       int* __restrict__ cursor,
                                                       int* __restrict__ csr_src) {
  int e = blockIdx.x * 256 + threadIdx.x;
  if (e < N_EDGES) {
    int d = ei[N_EDGES + e];
    int p = atomicAdd(&cursor[d], 1);
    csr_src[rowoff[d] + p] = ei[e];
  }
}

// ---------------- fp32 -> split bf16 conversions ----------------

__global__ __launch_bounds__(256) void convert_x_kernel(const float* __restrict__ x,
                                                        unsigned short* __restrict__ Ah,
                                                        unsigned short* __restrict__ Al) {
  size_t i4 = ((size_t)blockIdx.x * 256 + threadIdx.x) * 4;
  int row = (int)(i4 >> 9);
  ushort4 h, l;
  if (row < N_NODES) {
    float4 v = *(const float4*)(x + i4);
    h.x = f2bf(v.x); l.x = f2bf(v.x - bf2f(h.x));
    h.y = f2bf(v.y); l.y = f2bf(v.y - bf2f(h.y));
    h.z = f2bf(v.z); l.z = f2bf(v.z - bf2f(h.z));
    h.w = f2bf(v.w); l.w = f2bf(v.w - bf2f(h.w));
  } else {
    h.x = h.y = h.z = h.w = 0;
    l.x = l.y = l.z = l.w = 0;
  }
  *(ushort4*)(Ah + i4) = h;
  *(ushort4*)(Al + i4) = l;
}

__global__ __launch_bounds__(256) void wconv_kernel(const float* __restrict__ W,
                                                    unsigned short* __restrict__ Bh,
                                                    unsigned short* __restrict__ Bl) {
  __shared__ float t[64][65];
  int n0 = blockIdx.x * 64, k0 = blockIdx.y * 64;
  int tid = threadIdx.x;
  int c = tid & 63, r4 = tid >> 6;
#pragma unroll
  for (int r = 0; r < 64; r += 4)
    t[r4 + r][c] = W[(size_t)(k0 + r4 + r) * D_FEAT + n0 + c];
  __syncthreads();
#pragma unroll
  for (int r = 0; r < 64; r += 4) {
    float v = t[c][r4 + r];
    unsigned short h = f2bf(v);
    size_t o = (size_t)(n0 + r4 + r) * D_FEAT + k0 + c;
    Bh[o] = h;
    Bl[o] = f2bf(v - bf2f(h));
  }
}

// ---------------- split-bf16 MFMA GEMM: Cbf[M,512] = bf16(A @ W + bias) ----------------

__global__ __launch_bounds__(256, 3) void mfma_gemm_kernel(
    const unsigned short* __restrict__ Ah, const unsigned short* __restrict__ Al,
    const unsigned short* __restrict__ Bh, const unsigned short* __restrict__ Bl,
    const float* __restrict__ bias, unsigned short* __restrict__ Cbf) {
  __shared__ unsigned short sAh[128 * 32], sAl[128 * 32], sBh[128 * 32], sBl[128 * 32];

  int tid = threadIdx.x;
  int wave = tid >> 6, lane = tid & 63;
  // blockIdx.x = N tile (4 of them, adjacent in dispatch -> A shared via L2/L3)
  int n0 = blockIdx.x * 128, m0 = blockIdx.y * 128;

  int r0 = (wave * 2 + 0) * 16 + (lane >> 2);
  int r1 = (wave * 2 + 1) * 16 + (lane >> 2);
  int s0 = (lane & 3) ^ ((r0 >> 1) & 3);
  int s1 = (lane & 3) ^ ((r1 >> 1) & 3);
  size_t gA0 = (size_t)(m0 + r0) * D_FEAT + s0 * 8;
  size_t gA1 = (size_t)(m0 + r1) * D_FEAT + s1 * 8;
  size_t gB0 = (size_t)(n0 + r0) * D_FEAT + s0 * 8;
  size_t gB1 = (size_t)(n0 + r1) * D_FEAT + s1 * 8;
  int l0 = (wave * 2 + 0) * 512;
  int l1 = (wave * 2 + 1) * 512;

  int q = lane >> 4, fr = lane & 15;
  int wm = (wave >> 1) * 64, wn = (wave & 1) * 64;
  int aoff[4], boff[4];
#pragma unroll
  for (int i = 0; i < 4; ++i) {
    int row = wm + i * 16 + fr;
    aoff[i] = row * 32 + (q ^ ((row >> 1) & 3)) * 8;
  }
#pragma unroll
  for (int j = 0; j < 4; ++j) {
    int row = wn + j * 16 + fr;
    boff[j] = row * 32 + (q ^ ((row >> 1) & 3)) * 8;
  }

  f32x4 acc[4][4];
#pragma unroll
  for (int i = 0; i < 4; ++i)
#pragma unroll
    for (int j = 0; j < 4; ++j) acc[i][j] = (f32x4)0.0f;

  for (int k0 = 0; k0 < D_FEAT; k0 += 32) {
    gl_lds16(Ah + gA0 + k0, sAh + l0);
    gl_lds16(Ah + gA1 + k0, sAh + l1);
    gl_lds16(Al + gA0 + k0, sAl + l0);
    gl_lds16(Al + gA1 + k0, sAl + l1);
    gl_lds16(Bh + gB0 + k0, sBh + l0);
    gl_lds16(Bh + gB1 + k0, sBh + l1);
    gl_lds16(Bl + gB0 + k0, sBl + l0);
    gl_lds16(Bl + gB1 + k0, sBl + l1);
    __syncthreads();

    short8 ah[4], bb[4], t[4];
#pragma unroll
    for (int i = 0; i < 4; ++i) ah[i] = *(const short8*)(sAh + aoff[i]);
#pragma unroll
    for (int j = 0; j < 4; ++j) bb[j] = *(const short8*)(sBh + boff[j]);
#pragma unroll
    for (int i = 0; i < 4; ++i)
#pragma unroll
      for (int j = 0; j < 4; ++j)
        acc[i][j] = __builtin_amdgcn_mfma_f32_16x16x32_bf16(ah[i], bb[j], acc[i][j], 0, 0, 0);
#pragma unroll
    for (int i = 0; i < 4; ++i) t[i] = *(const short8*)(sAl + aoff[i]);
#pragma unroll
    for (int i = 0; i < 4; ++i)
#pragma unroll
      for (int j = 0; j < 4; ++j)
        acc[i][j] = __builtin_amdgcn_mfma_f32_16x16x32_bf16(t[i], bb[j], acc[i][j], 0, 0, 0);
#pragma unroll
    for (int j = 0; j < 4; ++j) bb[j] = *(const short8*)(sBl + boff[j]);
#pragma unroll
    for (int i = 0; i < 4; ++i)
#pragma unroll
      for (int j = 0; j < 4; ++j)
        acc[i][j] = __builtin_amdgcn_mfma_f32_16x16x32_bf16(ah[i], bb[j], acc[i][j], 0, 0, 0);
    __syncthreads();
  }

  float bj[4];
#pragma unroll
  for (int j = 0; j < 4; ++j) bj[j] = bias[n0 + wn + j * 16 + fr];
#pragma unroll
  for (int i = 0; i < 4; ++i) {
    int gm0 = m0 + wm + i * 16 + q * 4;
#pragma unroll
    for (int j = 0; j < 4; ++j) {
      int gn = n0 + wn + j * 16 + fr;
#pragma unroll
      for (int r = 0; r < 4; ++r) {
        int gm = gm0 + r;
        if (gm < N_NODES) Cbf[(size_t)gm * D_FEAT + gn] = f2bf(acc[i][j][r] + bj[j]);
      }
    }
  }
}

// ---------------- fused aggregate + self-loop + LayerNorm + ReLU ----------------
// one WAVE per node (2 nodes / 128-thread block); ht is bf16; shuffle-only LN.

template <bool LAST>
__global__ __launch_bounds__(128) void agg_ln_relu_kernel(
    const unsigned short* __restrict__ ht, const int* __restrict__ rowoff,
    const int* __restrict__ csr_src, const float* __restrict__ inv_sqrt,
    const float* __restrict__ gamma, const float* __restrict__ beta,
    float* __restrict__ hout, unsigned short* __restrict__ ph,
    unsigned short* __restrict__ pl) {
  int n = blockIdx.x * 2 + (threadIdx.x >> 6);
  int lane = threadIdx.x & 63;
  int c8 = lane * 8;

  float acc[8];
#pragma unroll
  for (int k = 0; k < 8; ++k) acc[k] = 0.f;

  int beg = rowoff[n];
  int end = rowoff[n + 1];
  float isn = inv_sqrt[n];

  int e = beg;
  for (; e + 2 <= end; e += 2) {
    int sa = csr_src[e], sb = csr_src[e + 1];
    float wa = isn * inv_sqrt[sa];
    float wb = isn * inv_sqrt[sb];
    u16x8 va = *(const u16x8*)(ht + (size_t)sa * D_FEAT + c8);
    u16x8 vb = *(const u16x8*)(ht + (size_t)sb * D_FEAT + c8);
#pragma unroll
    for (int k = 0; k < 8; ++k) acc[k] = fmaf(wa, bf2f(va[k]), acc[k]);
#pragma unroll
    for (int k = 0; k < 8; ++k) acc[k] = fmaf(wb, bf2f(vb[k]), acc[k]);
  }
  if (e < end) {
    int sa = csr_src[e];
    float wa = isn * inv_sqrt[sa];
    u16x8 va = *(const u16x8*)(ht + (size_t)sa * D_FEAT + c8);
#pragma unroll
    for (int k = 0; k < 8; ++k) acc[k] = fmaf(wa, bf2f(va[k]), acc[k]);
  }
  {
    float w = isn * isn;  // self-loop 1/deg
    u16x8 v = *(const u16x8*)(ht + (size_t)n * D_FEAT + c8);
#pragma unroll
    for (int k = 0; k < 8; ++k) acc[k] = fmaf(w, bf2f(v[k]), acc[k]);
  }

  float s = 0.f, s2 = 0.f;
#pragma unroll
  for (int k = 0; k < 8; ++k) { s += acc[k]; s2 += acc[k] * acc[k]; }
#pragma unroll
  for (int off = 32; off > 0; off >>= 1) {
    s += __shfl_xor(s, off);
    s2 += __shfl_xor(s2, off);
  }

  const float inv_d = 1.0f / (float)D_FEAT;
  float mu = s * inv_d;
  float var = s2 * inv_d - mu * mu;
  float rstd = rsqrtf(var + LN_EPS);

  float o[8];
#pragma unroll
  for (int k = 0; k < 8; ++k) {
    float g = gamma[c8 + k];
    float b = beta[c8 + k];
    o[k] = fmaxf(g * (acc[k] - mu) * rstd + b, 0.f);
  }

  if (LAST) {
    float4 o0 = make_float4(o[0], o[1], o[2], o[3]);
    float4 o1 = make_float4(o[4], o[5], o[6], o[7]);
    *(float4*)(hout + (size_t)n * D_FEAT + c8) = o0;
    *(float4*)(hout + (size_t)n * D_FEAT + c8 + 4) = o1;
  } else {
    u16x8 h, l;
#pragma unroll
    for (int k = 0; k < 8; ++k) {
      unsigned short hh = f2bf(o[k]);
      h[k] = hh;
      l[k] = f2bf(o[k] - bf2f(hh));
    }
    size_t off = (size_t)n * D_FEAT + c8;
    *(u16x8*)(ph + off) = h;
    *(u16x8*)(pl + off) = l;
  }
}

// ---------------- launch ----------------

extern "C" void kernel_launch(void* const* d_in, const int* in_sizes, int n_in,
                              void* d_out, int out_size, void* d_ws, size_t ws_size,
                              hipStream_t stream) {
  const float* x      = (const float*)d_in[0];
  const int*   ei     = (const int*)d_in[1];
  const float* Ws     = (const float*)d_in[2];
  const float* bs     = (const float*)d_in[3];
  const float* gammas = (const float*)d_in[4];
  const float* betas  = (const float*)d_in[5];
  float* out = (float*)d_out;

  unsigned short* Ah  = (unsigned short*)d_ws;                   // M_PAD*512
  unsigned short* Al  = Ah + (size_t)M_PAD * D_FEAT;             // M_PAD*512
  unsigned short* Bth = Al + (size_t)M_PAD * D_FEAT;             // 512*512
  unsigned short* Btl = Bth + (size_t)D_FEAT * D_FEAT;           // 512*512
  unsigned short* htb = Btl + (size_t)D_FEAT * D_FEAT;           // N_NODES*512 bf16
  int* deg_cnt  = (int*)(htb + (size_t)N_NODES * D_FEAT);
  int* rowoff   = deg_cnt + N_NODES;
  int* cursor   = rowoff + (N_NODES + 1);
  int* csr_src  = cursor + N_NODES;
  float* inv_sqrt = (float*)(csr_src + N_EDGES);

  hipMemsetAsync(deg_cnt, 0, N_NODES * sizeof(int), stream);
  hipMemsetAsync(cursor, 0, N_NODES * sizeof(int), stream);

  count_deg_kernel<<<(N_EDGES + 255) / 256, 256, 0, stream>>>(ei, deg_cnt);
  scan_kernel<<<1, 1024, 0, stream>>>(deg_cnt, rowoff, inv_sqrt);
  fill_csr_kernel<<<(N_EDGES + 255) / 256, 256, 0, stream>>>(ei, rowoff, cursor, csr_src);

  convert_x_kernel<<<(M_PAD * D_FEAT / 4) / 256, 256, 0, stream>>>(x, Ah, Al);

  dim3 ggrid(D_FEAT / 128, M_PAD / 128);  // x = N tile (adjacent share A)
  for (int l = 0; l < N_LAYERS; ++l) {
    wconv_kernel<<<dim3(8, 8), 256, 0, stream>>>(Ws + (size_t)l * D_FEAT * D_FEAT, Bth, Btl);
    mfma_gemm_kernel<<<ggrid, 256, 0, stream>>>(Ah, Al, Bth, Btl, bs + (size_t)l * D_FEAT, htb);
    if (l < N_LAYERS - 1) {
      agg_ln_relu_kernel<false><<<N_NODES / 2, 128, 0, stream>>>(
          htb, rowoff, csr_src, inv_sqrt, gammas + (size_t)l * D_FEAT,
          betas + (size_t)l * D_FEAT, nullptr, Ah, Al);
    } else {
      agg_ln_relu_kernel<true><<<N_NODES / 2, 128, 0, stream>>>(
          htb, rowoff, csr_src, inv_sqrt, gammas + (size_t)l * D_FEAT,
          betas + (size_t)l * D_FEAT, out, nullptr, nullptr);
    }
  }
}

// Round 4
// 958.457 us; speedup vs baseline: 2.1950x; 1.0751x over previous
//
#include <hip/hip_runtime.h>

#define N_NODES 50000
#define N_EDGES 800000
#define D_FEAT 512
#define N_LAYERS 3
#define LN_EPS 1e-5f
#define M_PAD 50048  // 391 * 128
#define N_SBLK ((N_NODES + 255) / 256)  // 196 scan blocks

typedef __attribute__((ext_vector_type(8))) short short8;
typedef __attribute__((ext_vector_type(8))) unsigned short u16x8;
typedef __attribute__((ext_vector_type(4))) float f32x4;

__device__ __forceinline__ unsigned short f2bf(float f) {
  union { float f; unsigned u; } v; v.f = f;
  unsigned r = v.u + 0x7fffu + ((v.u >> 16) & 1u);  // RNE
  return (unsigned short)(r >> 16);
}
__device__ __forceinline__ float bf2f(unsigned short b) {
  union { unsigned u; float f; } v; v.u = ((unsigned)b) << 16;
  return v.f;
}

__device__ __forceinline__ void gl_lds16(const unsigned short* g, unsigned short* l) {
  __builtin_amdgcn_global_load_lds((const __attribute__((address_space(1))) unsigned int*)g,
                                   (__attribute__((address_space(3))) unsigned int*)l, 16, 0, 0);
}

// ---------------- graph preprocessing ----------------

__global__ __launch_bounds__(256) void count_deg_kernel(const int* __restrict__ ei,
                                                        int* __restrict__ cnt) {
  int e = blockIdx.x * 256 + threadIdx.x;
  if (e < N_EDGES) atomicAdd(&cnt[ei[N_EDGES + e]], 1);
}

// two-level scan: (1) per-block sums
__global__ __launch_bounds__(256) void block_sum_kernel(const int* __restrict__ cnt,
                                                        int* __restrict__ bsum) {
  int i = blockIdx.x * 256 + threadIdx.x;
  int v = (i < N_NODES) ? cnt[i] : 0;
#pragma unroll
  for (int off = 32; off > 0; off >>= 1) v += __shfl_down(v, off);
  __shared__ int w[4];
  if ((threadIdx.x & 63) == 0) w[threadIdx.x >> 6] = v;
  __syncthreads();
  if (threadIdx.x == 0) bsum[blockIdx.x] = w[0] + w[1] + w[2] + w[3];
}

// (2) scan the 196 block sums in one block; also writes rowoff[N_NODES] = total
__global__ __launch_bounds__(256) void scan_bsum_kernel(const int* __restrict__ bsum,
                                                        int* __restrict__ boff,
                                                        int* __restrict__ rowoff) {
  __shared__ int sd[256];
  int t = threadIdx.x;
  int v = (t < N_SBLK) ? bsum[t] : 0;
  sd[t] = v;
  __syncthreads();
#pragma unroll
  for (int off = 1; off < 256; off <<= 1) {
    int x = (t >= off) ? sd[t - off] : 0;
    __syncthreads();
    sd[t] += x;
    __syncthreads();
  }
  if (t < N_SBLK) boff[t] = sd[t] - v;
  if (t == 255) rowoff[N_NODES] = sd[255];
}

// (3) intra-block exclusive scan + add block offset; emit rowoff and inv_sqrt
__global__ __launch_bounds__(256) void scan_final_kernel(const int* __restrict__ cnt,
                                                         const int* __restrict__ boff,
                                                         int* __restrict__ rowoff,
                                                         float* __restrict__ inv_sqrt) {
  __shared__ int sd[256];
  int t = threadIdx.x;
  int i = blockIdx.x * 256 + t;
  int v = (i < N_NODES) ? cnt[i] : 0;
  sd[t] = v;
  __syncthreads();
#pragma unroll
  for (int off = 1; off < 256; off <<= 1) {
    int x = (t >= off) ? sd[t - off] : 0;
    __syncthreads();
    sd[t] += x;
    __syncthreads();
  }
  if (i < N_NODES) {
    rowoff[i] = boff[blockIdx.x] + sd[t] - v;
    inv_sqrt[i] = rsqrtf(1.0f + (float)v);
  }
}

__global__ __launch_bounds__(256) void fill_csr_kernel(const int* __restrict__ ei,
                                                       const int* __restrict__ rowoff,
                                                       int* __restrict__ cursor,
                                                       int* __restrict__ csr_src) {
  int e = blockIdx.x * 256 + threadIdx.x;
  if (e < N_EDGES) {
    int d = ei[N_EDGES + e];
    int p = atomicAdd(&cursor[d], 1);
    csr_src[rowoff[d] + p] = ei[e];
  }
}

// ---------------- fp32 -> split bf16 conversions ----------------

__global__ __launch_bounds__(256) void convert_x_kernel(const float* __restrict__ x,
                                                        unsigned short* __restrict__ Ah,
                                                        unsigned short* __restrict__ Al) {
  size_t i4 = ((size_t)blockIdx.x * 256 + threadIdx.x) * 4;
  int row = (int)(i4 >> 9);
  ushort4 h, l;
  if (row < N_NODES) {
    float4 v = *(const float4*)(x + i4);
    h.x = f2bf(v.x); l.x = f2bf(v.x - bf2f(h.x));
    h.y = f2bf(v.y); l.y = f2bf(v.y - bf2f(h.y));
    h.z = f2bf(v.z); l.z = f2bf(v.z - bf2f(h.z));
    h.w = f2bf(v.w); l.w = f2bf(v.w - bf2f(h.w));
  } else {
    h.x = h.y = h.z = h.w = 0;
    l.x = l.y = l.z = l.w = 0;
  }
  *(ushort4*)(Ah + i4) = h;
  *(ushort4*)(Al + i4) = l;
}

__global__ __launch_bounds__(256) void wconv_kernel(const float* __restrict__ W,
                                                    unsigned short* __restrict__ Bh,
                                                    unsigned short* __restrict__ Bl) {
  __shared__ float t[64][65];
  int n0 = blockIdx.x * 64, k0 = blockIdx.y * 64;
  int tid = threadIdx.x;
  int c = tid & 63, r4 = tid >> 6;
#pragma unroll
  for (int r = 0; r < 64; r += 4)
    t[r4 + r][c] = W[(size_t)(k0 + r4 + r) * D_FEAT + n0 + c];
  __syncthreads();
#pragma unroll
  for (int r = 0; r < 64; r += 4) {
    float v = t[c][r4 + r];
    unsigned short h = f2bf(v);
    size_t o = (size_t)(n0 + r4 + r) * D_FEAT + k0 + c;
    Bh[o] = h;
    Bl[o] = f2bf(v - bf2f(h));
  }
}

// ---------------- split-bf16 MFMA GEMM: Cbf[M,512] = bf16(A @ W + bias) ----------------

__global__ __launch_bounds__(256, 3) void mfma_gemm_kernel(
    const unsigned short* __restrict__ Ah, const unsigned short* __restrict__ Al,
    const unsigned short* __restrict__ Bh, const unsigned short* __restrict__ Bl,
    const float* __restrict__ bias, unsigned short* __restrict__ Cbf) {
  __shared__ unsigned short sAh[128 * 32], sAl[128 * 32], sBh[128 * 32], sBl[128 * 32];

  int tid = threadIdx.x;
  int wave = tid >> 6, lane = tid & 63;
  int n0 = blockIdx.x * 128, m0 = blockIdx.y * 128;

  int r0 = (wave * 2 + 0) * 16 + (lane >> 2);
  int r1 = (wave * 2 + 1) * 16 + (lane >> 2);
  int s0 = (lane & 3) ^ ((r0 >> 1) & 3);
  int s1 = (lane & 3) ^ ((r1 >> 1) & 3);
  size_t gA0 = (size_t)(m0 + r0) * D_FEAT + s0 * 8;
  size_t gA1 = (size_t)(m0 + r1) * D_FEAT + s1 * 8;
  size_t gB0 = (size_t)(n0 + r0) * D_FEAT + s0 * 8;
  size_t gB1 = (size_t)(n0 + r1) * D_FEAT + s1 * 8;
  int l0 = (wave * 2 + 0) * 512;
  int l1 = (wave * 2 + 1) * 512;

  int q = lane >> 4, fr = lane & 15;
  int wm = (wave >> 1) * 64, wn = (wave & 1) * 64;
  int aoff[4], boff[4];
#pragma unroll
  for (int i = 0; i < 4; ++i) {
    int row = wm + i * 16 + fr;
    aoff[i] = row * 32 + (q ^ ((row >> 1) & 3)) * 8;
  }
#pragma unroll
  for (int j = 0; j < 4; ++j) {
    int row = wn + j * 16 + fr;
    boff[j] = row * 32 + (q ^ ((row >> 1) & 3)) * 8;
  }

  f32x4 acc[4][4];
#pragma unroll
  for (int i = 0; i < 4; ++i)
#pragma unroll
    for (int j = 0; j < 4; ++j) acc[i][j] = (f32x4)0.0f;

  for (int k0 = 0; k0 < D_FEAT; k0 += 32) {
    gl_lds16(Ah + gA0 + k0, sAh + l0);
    gl_lds16(Ah + gA1 + k0, sAh + l1);
    gl_lds16(Al + gA0 + k0, sAl + l0);
    gl_lds16(Al + gA1 + k0, sAl + l1);
    gl_lds16(Bh + gB0 + k0, sBh + l0);
    gl_lds16(Bh + gB1 + k0, sBh + l1);
    gl_lds16(Bl + gB0 + k0, sBl + l0);
    gl_lds16(Bl + gB1 + k0, sBl + l1);
    __syncthreads();

    short8 ah[4], bb[4], t[4];
#pragma unroll
    for (int i = 0; i < 4; ++i) ah[i] = *(const short8*)(sAh + aoff[i]);
#pragma unroll
    for (int j = 0; j < 4; ++j) bb[j] = *(const short8*)(sBh + boff[j]);
#pragma unroll
    for (int i = 0; i < 4; ++i)
#pragma unroll
      for (int j = 0; j < 4; ++j)
        acc[i][j] = __builtin_amdgcn_mfma_f32_16x16x32_bf16(ah[i], bb[j], acc[i][j], 0, 0, 0);
#pragma unroll
    for (int i = 0; i < 4; ++i) t[i] = *(const short8*)(sAl + aoff[i]);
#pragma unroll
    for (int i = 0; i < 4; ++i)
#pragma unroll
      for (int j = 0; j < 4; ++j)
        acc[i][j] = __builtin_amdgcn_mfma_f32_16x16x32_bf16(t[i], bb[j], acc[i][j], 0, 0, 0);
#pragma unroll
    for (int j = 0; j < 4; ++j) bb[j] = *(const short8*)(sBl + boff[j]);
#pragma unroll
    for (int i = 0; i < 4; ++i)
#pragma unroll
      for (int j = 0; j < 4; ++j)
        acc[i][j] = __builtin_amdgcn_mfma_f32_16x16x32_bf16(ah[i], bb[j], acc[i][j], 0, 0, 0);
    __syncthreads();
  }

  float bj[4];
#pragma unroll
  for (int j = 0; j < 4; ++j) bj[j] = bias[n0 + wn + j * 16 + fr];
#pragma unroll
  for (int i = 0; i < 4; ++i) {
    int gm0 = m0 + wm + i * 16 + q * 4;
#pragma unroll
    for (int j = 0; j < 4; ++j) {
      int gn = n0 + wn + j * 16 + fr;
#pragma unroll
      for (int r = 0; r < 4; ++r) {
        int gm = gm0 + r;
        if (gm < N_NODES) Cbf[(size_t)gm * D_FEAT + gn] = f2bf(acc[i][j][r] + bj[j]);
      }
    }
  }
}

// ---------------- fused aggregate + self-loop + LayerNorm + ReLU ----------------

template <bool LAST>
__global__ __launch_bounds__(128) void agg_ln_relu_kernel(
    const unsigned short* __restrict__ ht, const int* __restrict__ rowoff,
    const int* __restrict__ csr_src, const float* __restrict__ inv_sqrt,
    const float* __restrict__ gamma, const float* __restrict__ beta,
    float* __restrict__ hout, unsigned short* __restrict__ ph,
    unsigned short* __restrict__ pl) {
  int n = blockIdx.x * 2 + (threadIdx.x >> 6);
  int lane = threadIdx.x & 63;
  int c8 = lane * 8;

  float acc[8];
#pragma unroll
  for (int k = 0; k < 8; ++k) acc[k] = 0.f;

  int beg = rowoff[n];
  int end = rowoff[n + 1];
  float isn = inv_sqrt[n];

  int e = beg;
  for (; e + 2 <= end; e += 2) {
    int sa = csr_src[e], sb = csr_src[e + 1];
    float wa = isn * inv_sqrt[sa];
    float wb = isn * inv_sqrt[sb];
    u16x8 va = *(const u16x8*)(ht + (size_t)sa * D_FEAT + c8);
    u16x8 vb = *(const u16x8*)(ht + (size_t)sb * D_FEAT + c8);
#pragma unroll
    for (int k = 0; k < 8; ++k) acc[k] = fmaf(wa, bf2f(va[k]), acc[k]);
#pragma unroll
    for (int k = 0; k < 8; ++k) acc[k] = fmaf(wb, bf2f(vb[k]), acc[k]);
  }
  if (e < end) {
    int sa = csr_src[e];
    float wa = isn * inv_sqrt[sa];
    u16x8 va = *(const u16x8*)(ht + (size_t)sa * D_FEAT + c8);
#pragma unroll
    for (int k = 0; k < 8; ++k) acc[k] = fmaf(wa, bf2f(va[k]), acc[k]);
  }
  {
    float w = isn * isn;
    u16x8 v = *(const u16x8*)(ht + (size_t)n * D_FEAT + c8);
#pragma unroll
    for (int k = 0; k < 8; ++k) acc[k] = fmaf(w, bf2f(v[k]), acc[k]);
  }

  float s = 0.f, s2 = 0.f;
#pragma unroll
  for (int k = 0; k < 8; ++k) { s += acc[k]; s2 += acc[k] * acc[k]; }
#pragma unroll
  for (int off = 32; off > 0; off >>= 1) {
    s += __shfl_xor(s, off);
    s2 += __shfl_xor(s2, off);
  }

  const float inv_d = 1.0f / (float)D_FEAT;
  float mu = s * inv_d;
  float var = s2 * inv_d - mu * mu;
  float rstd = rsqrtf(var + LN_EPS);

  float o[8];
#pragma unroll
  for (int k = 0; k < 8; ++k) {
    float g = gamma[c8 + k];
    float b = beta[c8 + k];
    o[k] = fmaxf(g * (acc[k] - mu) * rstd + b, 0.f);
  }

  if (LAST) {
    float4 o0 = make_float4(o[0], o[1], o[2], o[3]);
    float4 o1 = make_float4(o[4], o[5], o[6], o[7]);
    *(float4*)(hout + (size_t)n * D_FEAT + c8) = o0;
    *(float4*)(hout + (size_t)n * D_FEAT + c8 + 4) = o1;
  } else {
    u16x8 h, l;
#pragma unroll
    for (int k = 0; k < 8; ++k) {
      unsigned short hh = f2bf(o[k]);
      h[k] = hh;
      l[k] = f2bf(o[k] - bf2f(hh));
    }
    size_t off = (size_t)n * D_FEAT + c8;
    *(u16x8*)(ph + off) = h;
    *(u16x8*)(pl + off) = l;
  }
}

// ---------------- launch ----------------

extern "C" void kernel_launch(void* const* d_in, const int* in_sizes, int n_in,
                              void* d_out, int out_size, void* d_ws, size_t ws_size,
                              hipStream_t stream) {
  const float* x      = (const float*)d_in[0];
  const int*   ei     = (const int*)d_in[1];
  const float* Ws     = (const float*)d_in[2];
  const float* bs     = (const float*)d_in[3];
  const float* gammas = (const float*)d_in[4];
  const float* betas  = (const float*)d_in[5];
  float* out = (float*)d_out;

  unsigned short* Ah  = (unsigned short*)d_ws;                   // M_PAD*512
  unsigned short* Al  = Ah + (size_t)M_PAD * D_FEAT;             // M_PAD*512
  unsigned short* Bth = Al + (size_t)M_PAD * D_FEAT;             // 512*512
  unsigned short* Btl = Bth + (size_t)D_FEAT * D_FEAT;           // 512*512
  unsigned short* htb = Btl + (size_t)D_FEAT * D_FEAT;           // N_NODES*512 bf16
  int* deg_cnt  = (int*)(htb + (size_t)N_NODES * D_FEAT);
  int* rowoff   = deg_cnt + N_NODES;
  int* cursor   = rowoff + (N_NODES + 1);
  int* csr_src  = cursor + N_NODES;
  float* inv_sqrt = (float*)(csr_src + N_EDGES);
  int* bsum     = (int*)(inv_sqrt + N_NODES);
  int* boff     = bsum + N_SBLK;

  hipMemsetAsync(deg_cnt, 0, N_NODES * sizeof(int), stream);
  hipMemsetAsync(cursor, 0, N_NODES * sizeof(int), stream);

  count_deg_kernel<<<(N_EDGES + 255) / 256, 256, 0, stream>>>(ei, deg_cnt);
  block_sum_kernel<<<N_SBLK, 256, 0, stream>>>(deg_cnt, bsum);
  scan_bsum_kernel<<<1, 256, 0, stream>>>(bsum, boff, rowoff);
  scan_final_kernel<<<N_SBLK, 256, 0, stream>>>(deg_cnt, boff, rowoff, inv_sqrt);
  fill_csr_kernel<<<(N_EDGES + 255) / 256, 256, 0, stream>>>(ei, rowoff, cursor, csr_src);

  convert_x_kernel<<<(M_PAD * D_FEAT / 4) / 256, 256, 0, stream>>>(x, Ah, Al);

  dim3 ggrid(D_FEAT / 128, M_PAD / 128);
  for (int l = 0; l < N_LAYERS; ++l) {
    wconv_kernel<<<dim3(8, 8), 256, 0, stream>>>(Ws + (size_t)l * D_FEAT * D_FEAT, Bth, Btl);
    mfma_gemm_kernel<<<ggrid, 256, 0, stream>>>(Ah, Al, Bth, Btl, bs + (size_t)l * D_FEAT, htb);
    if (l < N_LAYERS - 1) {
      agg_ln_relu_kernel<false><<<N_NODES / 2, 128, 0, stream>>>(
          htb, rowoff, csr_src, inv_sqrt, gammas + (size_t)l * D_FEAT,
          betas + (size_t)l * D_FEAT, nullptr, Ah, Al);
    } else {
      agg_ln_relu_kernel<true><<<N_NODES / 2, 128, 0, stream>>>(
          htb, rowoff, csr_src, inv_sqrt, gammas + (size_t)l * D_FEAT,
          betas + (size_t)l * D_FEAT, out, nullptr, nullptr);
    }
  }
}